// Round 12
// baseline (2334.922 us; speedup 1.0000x reference)
//
#include <hip/hip_runtime.h>
#include <hip/hip_bf16.h>
#include <math.h>

#define B_ 32
#define N_ 256
#define DIM_ 384
#define H_ 6
#define DH_ 64
#define INNER_ 384
#define MLP_ 1536
#define DEPTH_ 12
#define T_ (B_ * N_)   // 8192 tokens

typedef __bf16 bf16x8 __attribute__((ext_vector_type(8)));
typedef __bf16 bf16x4 __attribute__((ext_vector_type(4)));
typedef float f32x4 __attribute__((ext_vector_type(4)));

// wbuf layout (bf16, per layer, transposed [n][k])
#define WQKV_OFF 0                      // [1152][384]
#define WO_OFF   (1152 * 384)           // [384][384]
#define W1_OFF   (WO_OFF + 384 * 384)   // [1536][384]
#define W2_OFF   (W1_OFF + 1536 * 384)  // [384][1536]
#define WBUF_ELEMS (W2_OFF + 384 * 1536)

// ---------------- weight pre-pack: fp32 [K][N] -> bf16 [n][k], one layer ----------------
__global__ __launch_bounds__(256) void convert_w(
    const float* __restrict__ wq, const float* __restrict__ wkv,
    const float* __restrict__ wo, const float* __restrict__ w1,
    const float* __restrict__ w2, __bf16* __restrict__ wbuf)
{
    __shared__ float til[64][65];
    int t = blockIdx.x;
    int lane = threadIdx.x & 63, seg = threadIdx.x >> 6;
    const float* src; __bf16* dst;
    int Ns, sc, dK, dR, k0;
    if (t < 108) {                      // wqkv_t [1152][384]
        int nt = t / 6, kt = t % 6;
        int n0 = nt * 64; k0 = kt * 64;
        dst = wbuf + WQKV_OFF; dK = 384; dR = n0;
        if (n0 < 384) { src = wq;  Ns = 384; sc = n0; }
        else          { src = wkv; Ns = 768; sc = n0 - 384; }
    } else if (t < 144) {               // wo_t [384][384]
        int u = t - 108; int nt = u / 6, kt = u % 6;
        src = wo; Ns = 384; sc = nt * 64;
        dst = wbuf + WO_OFF; dK = 384; dR = nt * 64; k0 = kt * 64;
    } else if (t < 288) {               // w1_t [1536][384]
        int u = t - 144; int nt = u / 6, kt = u % 6;
        src = w1; Ns = 1536; sc = nt * 64;
        dst = wbuf + W1_OFF; dK = 384; dR = nt * 64; k0 = kt * 64;
    } else {                            // w2_t [384][1536]
        int u = t - 288; int nt = u / 24, kt = u % 24;
        src = w2; Ns = 384; sc = nt * 64;
        dst = wbuf + W2_OFF; dK = 1536; dR = nt * 64; k0 = kt * 64;
    }
    #pragma unroll
    for (int r = 0; r < 16; ++r) {
        int i = seg * 16 + r;
        til[i][lane] = src[(size_t)(k0 + i) * Ns + sc + lane];
    }
    __syncthreads();
    #pragma unroll
    for (int r = 0; r < 16; ++r) {
        int i = seg * 16 + r;
        dst[(size_t)(dR + i) * dK + k0 + lane] = (__bf16)til[lane][i];
    }
}

// ---------------- layernorm: one WAVE per token; fp32 in, bf16 out ----------
__global__ __launch_bounds__(64) void ln1w(
    const float* __restrict__ x, const float* __restrict__ g,
    const float* __restrict__ b, __bf16* __restrict__ y)
{
    size_t row = blockIdx.x;
    int lane = threadIdx.x;
    const float* xr = x + row * DIM_;
    float v[6];
    #pragma unroll
    for (int s = 0; s < 6; ++s) v[s] = xr[lane + 64 * s];
    float sum = 0.f;
    #pragma unroll
    for (int s = 0; s < 6; ++s) sum += v[s];
    #pragma unroll
    for (int o = 32; o > 0; o >>= 1) sum += __shfl_xor(sum, o);
    float mu = sum * (1.0f / DIM_);
    float var = 0.f;
    #pragma unroll
    for (int s = 0; s < 6; ++s) { float d = v[s] - mu; var += d * d; }
    #pragma unroll
    for (int o = 32; o > 0; o >>= 1) var += __shfl_xor(var, o);
    float rs = rsqrtf(var * (1.0f / DIM_) + 1e-5f);
    __bf16* yr = y + row * DIM_;
    #pragma unroll
    for (int s = 0; s < 6; ++s) {
        int e = lane + 64 * s;
        yr[e] = (__bf16)((v[s] - mu) * rs * g[e] + b[e]);
    }
}

// ---------------- 128x128 LDS double-buffered MFMA GEMM, XCD-swizzled 1-D grid ----------
#define LDK 40   // padded k-stride: 80 B rows

template<int MODE>
__global__ __launch_bounds__(256) void gemm128(
    const __bf16* __restrict__ A, const __bf16* __restrict__ Bt,
    const float* __restrict__ bias, const float* __restrict__ ls,
    float* __restrict__ xf, __bf16* __restrict__ out,
    __bf16* __restrict__ oq, __bf16* __restrict__ ok, __bf16* __restrict__ ov,
    int K, int Nn)
{
    __shared__ __bf16 sA[2][128 * LDK];
    __shared__ __bf16 sB[2][128 * LDK];
    int id = blockIdx.x;
    int g = id & 7, j = id >> 3;
    int bm = (g + ((j & 7) << 3)) << 7;     // bmIdx in [0,64): g + 8*(j&7)
    int bn = (j >> 3) << 7;
    int tid = threadIdx.x;
    int lane = tid & 63, wid = tid >> 6;
    int wm = (wid & 1) * 64, wn = (wid >> 1) * 64;
    int fm = lane & 15, fq = lane >> 4;

    f32x4 acc[4][4] = {};

    int sr = tid >> 1, sh = (tid & 1) << 4;
    const __bf16* aSrc = A + (size_t)(bm + sr) * K + sh;
    const __bf16* bSrc = Bt + (size_t)(bn + sr) * K + sh;
    int soff = sr * LDK + sh;

    int nIter = K >> 5;

    {
        bf16x8 a0 = *(const bf16x8*)(aSrc);
        bf16x8 a1 = *(const bf16x8*)(aSrc + 8);
        bf16x8 b0 = *(const bf16x8*)(bSrc);
        bf16x8 b1 = *(const bf16x8*)(bSrc + 8);
        *(bf16x8*)&sA[0][soff]     = a0;
        *(bf16x8*)&sA[0][soff + 8] = a1;
        *(bf16x8*)&sB[0][soff]     = b0;
        *(bf16x8*)&sB[0][soff + 8] = b1;
    }
    bf16x8 pa0 = *(const bf16x8*)(aSrc + 32);
    bf16x8 pa1 = *(const bf16x8*)(aSrc + 40);
    bf16x8 pb0 = *(const bf16x8*)(bSrc + 32);
    bf16x8 pb1 = *(const bf16x8*)(bSrc + 40);
    __syncthreads();

    #pragma unroll 2
    for (int i = 0; i < nIter; ++i) {
        int cur = i & 1, nxt = cur ^ 1;
        bf16x8 af[4], bf[4];
        #pragma unroll
        for (int ii = 0; ii < 4; ++ii)
            af[ii] = *(const bf16x8*)&sA[cur][(wm + ii * 16 + fm) * LDK + fq * 8];
        #pragma unroll
        for (int jj = 0; jj < 4; ++jj)
            bf[jj] = *(const bf16x8*)&sB[cur][(wn + jj * 16 + fm) * LDK + fq * 8];
        if (i + 1 < nIter) {
            *(bf16x8*)&sA[nxt][soff]     = pa0;
            *(bf16x8*)&sA[nxt][soff + 8] = pa1;
            *(bf16x8*)&sB[nxt][soff]     = pb0;
            *(bf16x8*)&sB[nxt][soff + 8] = pb1;
        }
        if (i + 2 < nIter) {
            int ko = (i + 2) << 5;
            pa0 = *(const bf16x8*)(aSrc + ko);
            pa1 = *(const bf16x8*)(aSrc + ko + 8);
            pb0 = *(const bf16x8*)(bSrc + ko);
            pb1 = *(const bf16x8*)(bSrc + ko + 8);
        }
        #pragma unroll
        for (int ii = 0; ii < 4; ++ii)
            #pragma unroll
            for (int jj = 0; jj < 4; ++jj)
                acc[ii][jj] = __builtin_amdgcn_mfma_f32_16x16x32_bf16(af[ii], bf[jj], acc[ii][jj], 0, 0, 0);
        if (i + 1 < nIter) __syncthreads();
    }

    #pragma unroll
    for (int jj = 0; jj < 4; ++jj) {
        int col = bn + wn + jj * 16 + fm;
        float bv = (MODE != 0) ? bias[col] : 0.0f;
        float lv = (MODE == 2) ? ls[col] : 0.0f;
        #pragma unroll
        for (int i = 0; i < 4; ++i) {
            #pragma unroll
            for (int r = 0; r < 4; ++r) {
                int row = bm + wm + i * 16 + fq * 4 + r;
                float v = acc[i][jj][r];
                if (MODE == 0) {
                    if (col < 384)      oq[(size_t)row * 384 + col] = (__bf16)v;
                    else if (col < 768) ok[(size_t)row * 384 + col - 384] = (__bf16)v;
                    else {
                        int bb = row >> 8, tj = row & 255;
                        ov[((size_t)bb * 384 + (col - 768)) * 256 + tj] = (__bf16)v;
                    }
                } else if (MODE == 1) {
                    v += bv;
                    v = 0.5f * v * (1.0f + erff(v * 0.70710678118f));
                    out[(size_t)row * Nn + col] = (__bf16)v;
                } else {
                    size_t idx = (size_t)row * Nn + col;
                    xf[idx] = (v + bv) * lv + xf[idx];
                }
            }
        }
    }
}

// ---------------- fused MFMA talking-heads attention v3 ----------------
// 8-query blocks, 1024 blocks XCD-pinned: b=(id&7)+8*((id>>3)&3), itile=id>>5.
// 384 thr = 6 waves, wave g computes PRE-MIXED scores directly:
//   S'_g = sum_h mp[h,g]*scale[h]*(Q_h . K_h)  ==  (per-slice-scaled Q) . K over full 384 d.
// K staged in LDS in 32-token chunks (coalesced, 6-wave reuse). Mask folded into softmax.
#define PAD_S 264
#define KPAD 392   // 32-token K chunk row stride (bf16 elems)

__global__ __launch_bounds__(384) void attn_mfma(
    const __bf16* __restrict__ q, const __bf16* __restrict__ kb,
    const __bf16* __restrict__ vT, const float* __restrict__ scale,
    const float* __restrict__ mp, const float* __restrict__ mq,
    __bf16* __restrict__ o)
{
    __shared__ __bf16 sbuf[48][PAD_S];     // premixed scores / probs: row = g*8 + m
    __shared__ __bf16 kch[32 * KPAD];      // K chunk: 32 tokens x 384 d (padded)
    __shared__ float smq[36];

    int id = blockIdx.x;
    int b = (id & 7) + ((id >> 3) & 3) * 8;
    int i0 = (id >> 5) * 8;
    int tid = threadIdx.x;
    int lane = tid & 63, wid = tid >> 6;
    int fm = lane & 15, fq = lane >> 4;
    int g = wid;

    if (tid < 36) smq[tid] = mq[tid];

    // per-wave premix coefficients (scale folded)
    float mh[6];
    #pragma unroll
    for (int h = 0; h < 6; ++h) mh[h] = mp[h * 6 + g] * scale[h];

    // A fragments: scaled Q rows (m = fm&7), full 384 d in 12 chunks of 32
    bf16x8 asf[12];
    #pragma unroll
    for (int kc = 0; kc < 12; ++kc) {
        bf16x8 v = *(const bf16x8*)&q[(size_t)(b * 256 + i0 + (fm & 7)) * 384 + kc * 32 + fq * 8];
        float s = mh[kc >> 1];
        bf16x8 r;
        #pragma unroll
        for (int e = 0; e < 8; ++e) r[e] = (__bf16)((float)v[e] * s);
        asf[kc] = r;
    }

    // ---- QK^T (premixed): 8 chunks of 32 tokens ----
    for (int c = 0; c < 8; ++c) {
        #pragma unroll
        for (int r = 0; r < 4; ++r) {
            int lin = r * 384 + tid;
            int row = lin / 48, seg = lin % 48;
            *(bf16x8*)&kch[row * KPAD + seg * 8] =
                *(const bf16x8*)&kb[(size_t)(b * 256 + c * 32 + row) * 384 + seg * 8];
        }
        __syncthreads();
        #pragma unroll
        for (int jt = 0; jt < 2; ++jt) {
            f32x4 a = {};
            #pragma unroll
            for (int kc = 0; kc < 12; ++kc) {
                bf16x8 bf = *(const bf16x8*)&kch[(jt * 16 + fm) * KPAD + kc * 32 + fq * 8];
                a = __builtin_amdgcn_mfma_f32_16x16x32_bf16(asf[kc], bf, a, 0, 0, 0);
            }
            if (fq < 2) {
                #pragma unroll
                for (int r = 0; r < 4; ++r)
                    sbuf[g * 8 + fq * 4 + r][c * 32 + jt * 16 + fm] = (__bf16)a[r];
            }
        }
        __syncthreads();
    }

    // ---- softmax over j (mask diag here): wave g owns rows g*8..g*8+7 ----
    #pragma unroll
    for (int rr = 0; rr < 8; ++rr) {
        int row = g * 8 + rr;
        int maskcol = i0 + rr;
        bf16x4 v4 = *(const bf16x4*)&sbuf[row][lane * 4];
        float v[4];
        #pragma unroll
        for (int e = 0; e < 4; ++e)
            v[e] = (lane * 4 + e == maskcol) ? -1e30f : (float)v4[e];
        float m = fmaxf(fmaxf(v[0], v[1]), fmaxf(v[2], v[3]));
        #pragma unroll
        for (int off = 32; off > 0; off >>= 1) m = fmaxf(m, __shfl_xor(m, off));
        float e0 = __expf(v[0] - m), e1 = __expf(v[1] - m);
        float e2 = __expf(v[2] - m), e3 = __expf(v[3] - m);
        float s = e0 + e1 + e2 + e3;
        #pragma unroll
        for (int off = 32; off > 0; off >>= 1) s += __shfl_xor(s, off);
        float inv = 1.0f / s;
        bf16x4 w4 = { (__bf16)(e0 * inv), (__bf16)(e1 * inv), (__bf16)(e2 * inv), (__bf16)(e3 * inv) };
        *(bf16x4*)&sbuf[row][lane * 4] = w4;
    }
    __syncthreads();

    // ---- post-softmax head mix (thread-local in-place) ----
    for (int idx = tid; idx < 2048; idx += 384) {
        int qq = idx >> 8, jx = idx & 255;
        float sv[6], ovv[6];
        #pragma unroll
        for (int h2 = 0; h2 < 6; ++h2) sv[h2] = (float)sbuf[h2 * 8 + qq][jx];
        #pragma unroll
        for (int gg = 0; gg < 6; ++gg) {
            float r2 = 0.f;
            #pragma unroll
            for (int h2 = 0; h2 < 6; ++h2) r2 += sv[h2] * smq[h2 * 6 + gg];
            ovv[gg] = r2;
        }
        #pragma unroll
        for (int gg = 0; gg < 6; ++gg) sbuf[gg * 8 + qq][jx] = (__bf16)ovv[gg];
    }
    __syncthreads();

    // ---- P @ V: wave g computes O_g[8][64]; V frags direct from global (L2-hot) ----
    f32x4 acco[4] = {};
    #pragma unroll
    for (int jc = 0; jc < 4; ++jc) {
        #pragma unroll
        for (int ks = 0; ks < 2; ++ks) {
            bf16x8 af = *(const bf16x8*)&sbuf[g * 8 + (fm & 7)][jc * 64 + ks * 32 + fq * 8];
            #pragma unroll
            for (int nt = 0; nt < 4; ++nt) {
                bf16x8 bf = *(const bf16x8*)&vT[(size_t)(b * 384 + g * 64 + nt * 16 + fm) * 256 + jc * 64 + ks * 32 + fq * 8];
                acco[nt] = __builtin_amdgcn_mfma_f32_16x16x32_bf16(af, bf, acco[nt], 0, 0, 0);
            }
        }
    }
    if (fq < 2) {
        #pragma unroll
        for (int nt = 0; nt < 4; ++nt)
            #pragma unroll
            for (int r = 0; r < 4; ++r)
                o[(size_t)(b * 256 + i0 + fq * 4 + r) * 384 + g * 64 + nt * 16 + fm] = (__bf16)acco[nt][r];
    }
}

extern "C" void kernel_launch(void* const* d_in, const int* in_sizes, int n_in,
                              void* d_out, int out_size, void* d_ws, size_t ws_size,
                              hipStream_t stream) {
    const float* x      = (const float*)d_in[0];
    const float* ln1_g  = (const float*)d_in[1];
    const float* ln1_b  = (const float*)d_in[2];
    const float* wq     = (const float*)d_in[3];
    const float* wkv    = (const float*)d_in[4];
    const float* scale  = (const float*)d_in[5];
    const float* mixp   = (const float*)d_in[6];
    const float* mixq   = (const float*)d_in[7];
    const float* wo     = (const float*)d_in[8];
    const float* bo     = (const float*)d_in[9];
    const float* ls1    = (const float*)d_in[10];
    const float* ln2_g  = (const float*)d_in[11];
    const float* ln2_b  = (const float*)d_in[12];
    const float* w1     = (const float*)d_in[13];
    const float* b1     = (const float*)d_in[14];
    const float* w2     = (const float*)d_in[15];
    const float* b2     = (const float*)d_in[16];
    const float* ls2    = (const float*)d_in[17];

    char* ws = (char*)d_ws;
    float*  xf = (float*)ws;                      ws += (size_t)T_ * DIM_ * 4;
    __bf16* y  = (__bf16*)ws;                     ws += (size_t)T_ * DIM_ * 2;
    __bf16* q  = (__bf16*)ws;                     ws += (size_t)T_ * DIM_ * 2;
    __bf16* kb = (__bf16*)ws;                     ws += (size_t)T_ * DIM_ * 2;
    __bf16* vT = (__bf16*)ws;                     ws += (size_t)T_ * DIM_ * 2;
    __bf16* o  = (__bf16*)ws;                     ws += (size_t)T_ * DIM_ * 2;
    __bf16* wbuf = (__bf16*)ws;                   ws += (size_t)WBUF_ELEMS * 2;
    __bf16* h  = q;   // MLP hidden [T][1536] overlays q+kb+vT+o (dead by then)

    size_t nBytes = (size_t)T_ * DIM_ * sizeof(float);
    hipMemcpyAsync(xf, x, nBytes, hipMemcpyDeviceToDevice, stream);

    for (int l = 0; l < DEPTH_; ++l) {
        convert_w<<<432, 256, 0, stream>>>(
            wq + (size_t)l * DIM_ * INNER_, wkv + (size_t)l * DIM_ * 2 * INNER_,
            wo + (size_t)l * INNER_ * DIM_, w1 + (size_t)l * DIM_ * MLP_,
            w2 + (size_t)l * MLP_ * DIM_, wbuf);

        ln1w<<<T_, 64, 0, stream>>>(xf, ln1_g + (size_t)l * DIM_, ln1_b + (size_t)l * DIM_, y);

        // QKV: 64 x 9 tiles = 576 blocks (XCD-swizzled 1-D grid)
        gemm128<0><<<64 * 9, 256, 0, stream>>>(
            y, wbuf + WQKV_OFF, nullptr, nullptr, nullptr, nullptr,
            q, kb, vT, DIM_, 1152);

        // attention: 1024 blocks (8 queries each), batch pinned to XCD
        attn_mfma<<<1024, 384, 0, stream>>>(
            q, kb, vT, scale + (size_t)l * H_,
            mixp + (size_t)l * H_ * H_, mixq + (size_t)l * H_ * H_, o);

        // O-proj: 64 x 3 = 192 blocks
        gemm128<2><<<64 * 3, 256, 0, stream>>>(
            o, wbuf + WO_OFF, bo + (size_t)l * DIM_, ls1 + (size_t)l * DIM_,
            xf, nullptr, nullptr, nullptr, nullptr, INNER_, DIM_);

        ln1w<<<T_, 64, 0, stream>>>(xf, ln2_g + (size_t)l * DIM_, ln2_b + (size_t)l * DIM_, y);

        // MLP1: 64 x 12 = 768 blocks
        gemm128<1><<<64 * 12, 256, 0, stream>>>(
            y, wbuf + W1_OFF, b1 + (size_t)l * MLP_, nullptr,
            nullptr, h, nullptr, nullptr, nullptr, DIM_, MLP_);

        // MLP2: 64 x 3 = 192 blocks
        gemm128<2><<<64 * 3, 256, 0, stream>>>(
            h, wbuf + W2_OFF, b2 + (size_t)l * DIM_, ls2 + (size_t)l * DIM_,
            xf, nullptr, nullptr, nullptr, nullptr, MLP_, DIM_);
    }

    hipMemcpyAsync(d_out, xf, nBytes, hipMemcpyDeviceToDevice, stream);
}

// Round 13
// 1999.681 us; speedup vs baseline: 1.1676x; 1.1676x over previous
//
#include <hip/hip_runtime.h>
#include <hip/hip_bf16.h>
#include <math.h>

#define B_ 32
#define N_ 256
#define DIM_ 384
#define H_ 6
#define DH_ 64
#define INNER_ 384
#define MLP_ 1536
#define DEPTH_ 12
#define T_ (B_ * N_)   // 8192 tokens

typedef __bf16 bf16x8 __attribute__((ext_vector_type(8)));
typedef __bf16 bf16x4 __attribute__((ext_vector_type(4)));
typedef float f32x4 __attribute__((ext_vector_type(4)));

// wbuf layout (bf16, per layer, transposed [n][k])
#define WQKV_OFF 0                      // [1152][384]
#define WO_OFF   (1152 * 384)           // [384][384]
#define W1_OFF   (WO_OFF + 384 * 384)   // [1536][384]
#define W2_OFF   (W1_OFF + 1536 * 384)  // [384][1536]
#define WBUF_ELEMS (W2_OFF + 384 * 1536)

// ---------------- weight pre-pack: fp32 [K][N] -> bf16 [n][k], one layer ----------------
__global__ __launch_bounds__(256) void convert_w(
    const float* __restrict__ wq, const float* __restrict__ wkv,
    const float* __restrict__ wo, const float* __restrict__ w1,
    const float* __restrict__ w2, __bf16* __restrict__ wbuf)
{
    __shared__ float til[64][65];
    int t = blockIdx.x;
    int lane = threadIdx.x & 63, seg = threadIdx.x >> 6;
    const float* src; __bf16* dst;
    int Ns, sc, dK, dR, k0;
    if (t < 108) {                      // wqkv_t [1152][384]
        int nt = t / 6, kt = t % 6;
        int n0 = nt * 64; k0 = kt * 64;
        dst = wbuf + WQKV_OFF; dK = 384; dR = n0;
        if (n0 < 384) { src = wq;  Ns = 384; sc = n0; }
        else          { src = wkv; Ns = 768; sc = n0 - 384; }
    } else if (t < 144) {               // wo_t [384][384]
        int u = t - 108; int nt = u / 6, kt = u % 6;
        src = wo; Ns = 384; sc = nt * 64;
        dst = wbuf + WO_OFF; dK = 384; dR = nt * 64; k0 = kt * 64;
    } else if (t < 288) {               // w1_t [1536][384]
        int u = t - 144; int nt = u / 6, kt = u % 6;
        src = w1; Ns = 1536; sc = nt * 64;
        dst = wbuf + W1_OFF; dK = 384; dR = nt * 64; k0 = kt * 64;
    } else {                            // w2_t [384][1536]
        int u = t - 288; int nt = u / 24, kt = u % 24;
        src = w2; Ns = 384; sc = nt * 64;
        dst = wbuf + W2_OFF; dK = 1536; dR = nt * 64; k0 = kt * 64;
    }
    #pragma unroll
    for (int r = 0; r < 16; ++r) {
        int i = seg * 16 + r;
        til[i][lane] = src[(size_t)(k0 + i) * Ns + sc + lane];
    }
    __syncthreads();
    #pragma unroll
    for (int r = 0; r < 16; ++r) {
        int i = seg * 16 + r;
        dst[(size_t)(dR + i) * dK + k0 + lane] = (__bf16)til[lane][i];
    }
}

// ---------------- layernorm: one WAVE per token; fp32 in, bf16 out ----------
__global__ __launch_bounds__(64) void ln1w(
    const float* __restrict__ x, const float* __restrict__ g,
    const float* __restrict__ b, __bf16* __restrict__ y)
{
    size_t row = blockIdx.x;
    int lane = threadIdx.x;
    const float* xr = x + row * DIM_;
    float v[6];
    #pragma unroll
    for (int s = 0; s < 6; ++s) v[s] = xr[lane + 64 * s];
    float sum = 0.f;
    #pragma unroll
    for (int s = 0; s < 6; ++s) sum += v[s];
    #pragma unroll
    for (int o = 32; o > 0; o >>= 1) sum += __shfl_xor(sum, o);
    float mu = sum * (1.0f / DIM_);
    float var = 0.f;
    #pragma unroll
    for (int s = 0; s < 6; ++s) { float d = v[s] - mu; var += d * d; }
    #pragma unroll
    for (int o = 32; o > 0; o >>= 1) var += __shfl_xor(var, o);
    float rs = rsqrtf(var * (1.0f / DIM_) + 1e-5f);
    __bf16* yr = y + row * DIM_;
    #pragma unroll
    for (int s = 0; s < 6; ++s) {
        int e = lane + 64 * s;
        yr[e] = (__bf16)((v[s] - mu) * rs * g[e] + b[e]);
    }
}

// ---------------- 128x128 LDS double-buffered MFMA GEMM, XCD-swizzled 1-D grid ----------
// K is a COMPILE-TIME template parameter: prefetch guards fold to constants, loop fully
// unrolls, addressing becomes immediate offsets.
#define LDK 40   // padded k-stride: 80 B rows

template<int MODE, int K>
__global__ __launch_bounds__(256) void gemm128(
    const __bf16* __restrict__ A, const __bf16* __restrict__ Bt,
    const float* __restrict__ bias, const float* __restrict__ ls,
    float* __restrict__ xf, __bf16* __restrict__ out,
    __bf16* __restrict__ oq, __bf16* __restrict__ ok, __bf16* __restrict__ ov,
    int Nn)
{
    __shared__ __bf16 sA[2][128 * LDK];
    __shared__ __bf16 sB[2][128 * LDK];
    int id = blockIdx.x;
    int g = id & 7, j = id >> 3;
    int bm = (g + ((j & 7) << 3)) << 7;     // bmIdx in [0,64): g + 8*(j&7)
    int bn = (j >> 3) << 7;
    int tid = threadIdx.x;
    int lane = tid & 63, wid = tid >> 6;
    int wm = (wid & 1) * 64, wn = (wid >> 1) * 64;
    int fm = lane & 15, fq = lane >> 4;

    f32x4 acc[4][4] = {};

    int sr = tid >> 1, sh = (tid & 1) << 4;
    const __bf16* aSrc = A + (size_t)(bm + sr) * K + sh;
    const __bf16* bSrc = Bt + (size_t)(bn + sr) * K + sh;
    int soff = sr * LDK + sh;

    constexpr int nIter = K >> 5;

    {
        bf16x8 a0 = *(const bf16x8*)(aSrc);
        bf16x8 a1 = *(const bf16x8*)(aSrc + 8);
        bf16x8 b0 = *(const bf16x8*)(bSrc);
        bf16x8 b1 = *(const bf16x8*)(bSrc + 8);
        *(bf16x8*)&sA[0][soff]     = a0;
        *(bf16x8*)&sA[0][soff + 8] = a1;
        *(bf16x8*)&sB[0][soff]     = b0;
        *(bf16x8*)&sB[0][soff + 8] = b1;
    }
    bf16x8 pa0 = *(const bf16x8*)(aSrc + 32);
    bf16x8 pa1 = *(const bf16x8*)(aSrc + 40);
    bf16x8 pb0 = *(const bf16x8*)(bSrc + 32);
    bf16x8 pb1 = *(const bf16x8*)(bSrc + 40);
    __syncthreads();

    #pragma unroll
    for (int i = 0; i < nIter; ++i) {
        int cur = i & 1, nxt = cur ^ 1;
        bf16x8 af[4], bf[4];
        #pragma unroll
        for (int ii = 0; ii < 4; ++ii)
            af[ii] = *(const bf16x8*)&sA[cur][(wm + ii * 16 + fm) * LDK + fq * 8];
        #pragma unroll
        for (int jj = 0; jj < 4; ++jj)
            bf[jj] = *(const bf16x8*)&sB[cur][(wn + jj * 16 + fm) * LDK + fq * 8];
        if (i + 1 < nIter) {
            *(bf16x8*)&sA[nxt][soff]     = pa0;
            *(bf16x8*)&sA[nxt][soff + 8] = pa1;
            *(bf16x8*)&sB[nxt][soff]     = pb0;
            *(bf16x8*)&sB[nxt][soff + 8] = pb1;
        }
        if (i + 2 < nIter) {
            int ko = (i + 2) << 5;
            pa0 = *(const bf16x8*)(aSrc + ko);
            pa1 = *(const bf16x8*)(aSrc + ko + 8);
            pb0 = *(const bf16x8*)(bSrc + ko);
            pb1 = *(const bf16x8*)(bSrc + ko + 8);
        }
        #pragma unroll
        for (int ii = 0; ii < 4; ++ii)
            #pragma unroll
            for (int jj = 0; jj < 4; ++jj)
                acc[ii][jj] = __builtin_amdgcn_mfma_f32_16x16x32_bf16(af[ii], bf[jj], acc[ii][jj], 0, 0, 0);
        if (i + 1 < nIter) __syncthreads();
    }

    // epilogue: C/D layout col=lane&15, row=(lane>>4)*4+reg
    #pragma unroll
    for (int jj = 0; jj < 4; ++jj) {
        int col = bn + wn + jj * 16 + fm;
        float bv = (MODE != 0) ? bias[col] : 0.0f;
        float lv = (MODE == 2) ? ls[col] : 0.0f;
        #pragma unroll
        for (int i = 0; i < 4; ++i) {
            #pragma unroll
            for (int r = 0; r < 4; ++r) {
                int row = bm + wm + i * 16 + fq * 4 + r;
                float v = acc[i][jj][r];
                if (MODE == 0) {
                    if (col < 384)      oq[(size_t)row * 384 + col] = (__bf16)v;
                    else if (col < 768) ok[(size_t)row * 384 + col - 384] = (__bf16)v;
                    else {
                        int bb = row >> 8, tj = row & 255;
                        ov[((size_t)bb * 384 + (col - 768)) * 256 + tj] = (__bf16)v;
                    }
                } else if (MODE == 1) {
                    v += bv;
                    v = 0.5f * v * (1.0f + erff(v * 0.70710678118f));
                    out[(size_t)row * Nn + col] = (__bf16)v;
                } else {
                    size_t idx = (size_t)row * Nn + col;
                    xf[idx] = (v + bv) * lv + xf[idx];
                }
            }
        }
    }
}

// ---------------- fused MFMA talking-heads attention (v2, XCD-batch-pinned) ----------------
// 1-D grid of 512. Decode: b = (id&7) + 8*((id>>3)&3); itile = id>>5.
// All 16 query-tiles of a batch run on XCD (b&7): K/V filled into ONE L2 (1.6 MB/XCD).
// 384 threads = 6 waves, wave = head. q, kb: bf16 [tok][384]; vT: bf16 [b][384][256].
#define PAD_S 264

__global__ __launch_bounds__(384) void attn_mfma(
    const __bf16* __restrict__ q, const __bf16* __restrict__ kb,
    const __bf16* __restrict__ vT, const float* __restrict__ scale,
    const float* __restrict__ mp, const float* __restrict__ mq,
    __bf16* __restrict__ o)
{
    __shared__ __bf16 sbuf[96][PAD_S];
    __shared__ float smp[36], smq[36];

    int id = blockIdx.x;
    int b = (id & 7) + ((id >> 3) & 3) * 8;
    int i0 = (id >> 5) * 16;
    int tid = threadIdx.x;
    int lane = tid & 63, wid = tid >> 6;
    int fm = lane & 15, fq = lane >> 4;

    if (tid < 36) {
        smp[tid] = mp[tid] * scale[tid / 6];   // fold per-head scale into pre-mix
        smq[tid] = mq[tid];
    }

    // ---- QK^T: wave h computes S_h[16][256] ----
    int h = wid;
    bf16x8 qf[2];
    #pragma unroll
    for (int ks = 0; ks < 2; ++ks)
        qf[ks] = *(const bf16x8*)&q[(size_t)(b * 256 + i0 + fm) * 384 + h * 64 + ks * 32 + fq * 8];
    #pragma unroll 4
    for (int jt = 0; jt < 16; ++jt) {
        f32x4 a = {};
        #pragma unroll
        for (int ks = 0; ks < 2; ++ks) {
            bf16x8 bf = *(const bf16x8*)&kb[(size_t)(b * 256 + jt * 16 + fm) * 384 + h * 64 + ks * 32 + fq * 8];
            a = __builtin_amdgcn_mfma_f32_16x16x32_bf16(qf[ks], bf, a, 0, 0, 0);
        }
        #pragma unroll
        for (int r = 0; r < 4; ++r)
            sbuf[h * 16 + fq * 4 + r][jt * 16 + fm] = (__bf16)a[r];
    }
    __syncthreads();

    // ---- pre-softmax head mix (+ diag mask); thread-local in-place ----
    for (int idx = tid; idx < 4096; idx += 384) {
        int qq = idx >> 8, jx = idx & 255;
        float sv[6], ovv[6];
        #pragma unroll
        for (int h2 = 0; h2 < 6; ++h2) sv[h2] = (float)sbuf[h2 * 16 + qq][jx];
        #pragma unroll
        for (int gg = 0; gg < 6; ++gg) {
            float r2 = 0.f;
            #pragma unroll
            for (int h2 = 0; h2 < 6; ++h2) r2 += sv[h2] * smp[h2 * 6 + gg];
            ovv[gg] = (jx == i0 + qq) ? -1e30f : r2;
        }
        #pragma unroll
        for (int gg = 0; gg < 6; ++gg) sbuf[gg * 16 + qq][jx] = (__bf16)ovv[gg];
    }
    __syncthreads();

    // ---- softmax over j: wave w owns rows w*16..w*16+15 ----
    for (int rr = 0; rr < 16; ++rr) {
        int row = wid * 16 + rr;
        bf16x4 v4 = *(const bf16x4*)&sbuf[row][lane * 4];
        float v0 = (float)v4[0], v1 = (float)v4[1], v2 = (float)v4[2], v3 = (float)v4[3];
        float m = fmaxf(fmaxf(v0, v1), fmaxf(v2, v3));
        #pragma unroll
        for (int off = 32; off > 0; off >>= 1) m = fmaxf(m, __shfl_xor(m, off));
        float e0 = __expf(v0 - m), e1 = __expf(v1 - m), e2 = __expf(v2 - m), e3 = __expf(v3 - m);
        float s = e0 + e1 + e2 + e3;
        #pragma unroll
        for (int off = 32; off > 0; off >>= 1) s += __shfl_xor(s, off);
        float inv = 1.0f / s;
        bf16x4 w4 = { (__bf16)(e0 * inv), (__bf16)(e1 * inv), (__bf16)(e2 * inv), (__bf16)(e3 * inv) };
        *(bf16x4*)&sbuf[row][lane * 4] = w4;
    }
    __syncthreads();

    // ---- post-softmax head mix ----
    for (int idx = tid; idx < 4096; idx += 384) {
        int qq = idx >> 8, jx = idx & 255;
        float sv[6], ovv[6];
        #pragma unroll
        for (int h2 = 0; h2 < 6; ++h2) sv[h2] = (float)sbuf[h2 * 16 + qq][jx];
        #pragma unroll
        for (int gg = 0; gg < 6; ++gg) {
            float r2 = 0.f;
            #pragma unroll
            for (int h2 = 0; h2 < 6; ++h2) r2 += sv[h2] * smq[h2 * 6 + gg];
            ovv[gg] = r2;
        }
        #pragma unroll
        for (int gg = 0; gg < 6; ++gg) sbuf[gg * 16 + qq][jx] = (__bf16)ovv[gg];
    }
    __syncthreads();

    // ---- P @ V: wave g computes O_g[16][64]; V frags direct from global (L2-hot) ----
    int gg = wid;
    f32x4 acco[4] = {};
    #pragma unroll
    for (int jc = 0; jc < 4; ++jc) {
        #pragma unroll
        for (int ks = 0; ks < 2; ++ks) {
            bf16x8 af = *(const bf16x8*)&sbuf[gg * 16 + fm][jc * 64 + ks * 32 + fq * 8];
            #pragma unroll
            for (int nt = 0; nt < 4; ++nt) {
                bf16x8 bf = *(const bf16x8*)&vT[(size_t)(b * 384 + gg * 64 + nt * 16 + fm) * 256 + jc * 64 + ks * 32 + fq * 8];
                acco[nt] = __builtin_amdgcn_mfma_f32_16x16x32_bf16(af, bf, acco[nt], 0, 0, 0);
            }
        }
    }
    #pragma unroll
    for (int nt = 0; nt < 4; ++nt)
        #pragma unroll
        for (int r = 0; r < 4; ++r)
            o[(size_t)(b * 256 + i0 + fq * 4 + r) * 384 + gg * 64 + nt * 16 + fm] = (__bf16)acco[nt][r];
}

extern "C" void kernel_launch(void* const* d_in, const int* in_sizes, int n_in,
                              void* d_out, int out_size, void* d_ws, size_t ws_size,
                              hipStream_t stream) {
    const float* x      = (const float*)d_in[0];
    const float* ln1_g  = (const float*)d_in[1];
    const float* ln1_b  = (const float*)d_in[2];
    const float* wq     = (const float*)d_in[3];
    const float* wkv    = (const float*)d_in[4];
    const float* scale  = (const float*)d_in[5];
    const float* mixp   = (const float*)d_in[6];
    const float* mixq   = (const float*)d_in[7];
    const float* wo     = (const float*)d_in[8];
    const float* bo     = (const float*)d_in[9];
    const float* ls1    = (const float*)d_in[10];
    const float* ln2_g  = (const float*)d_in[11];
    const float* ln2_b  = (const float*)d_in[12];
    const float* w1     = (const float*)d_in[13];
    const float* b1     = (const float*)d_in[14];
    const float* w2     = (const float*)d_in[15];
    const float* b2     = (const float*)d_in[16];
    const float* ls2    = (const float*)d_in[17];

    char* ws = (char*)d_ws;
    float*  xf = (float*)ws;                      ws += (size_t)T_ * DIM_ * 4;
    __bf16* y  = (__bf16*)ws;                     ws += (size_t)T_ * DIM_ * 2;
    __bf16* q  = (__bf16*)ws;                     ws += (size_t)T_ * DIM_ * 2;
    __bf16* kb = (__bf16*)ws;                     ws += (size_t)T_ * DIM_ * 2;
    __bf16* vT = (__bf16*)ws;                     ws += (size_t)T_ * DIM_ * 2;
    __bf16* o  = (__bf16*)ws;                     ws += (size_t)T_ * DIM_ * 2;
    __bf16* wbuf = (__bf16*)ws;                   ws += (size_t)WBUF_ELEMS * 2;
    __bf16* h  = q;   // MLP hidden [T][1536] overlays q+kb+vT+o (dead by then)

    size_t nBytes = (size_t)T_ * DIM_ * sizeof(float);
    hipMemcpyAsync(xf, x, nBytes, hipMemcpyDeviceToDevice, stream);

    for (int l = 0; l < DEPTH_; ++l) {
        convert_w<<<432, 256, 0, stream>>>(
            wq + (size_t)l * DIM_ * INNER_, wkv + (size_t)l * DIM_ * 2 * INNER_,
            wo + (size_t)l * INNER_ * DIM_, w1 + (size_t)l * DIM_ * MLP_,
            w2 + (size_t)l * MLP_ * DIM_, wbuf);

        ln1w<<<T_, 64, 0, stream>>>(xf, ln1_g + (size_t)l * DIM_, ln1_b + (size_t)l * DIM_, y);

        // QKV: 64 x 9 tiles = 576 blocks (XCD-swizzled 1-D grid)
        gemm128<0, 384><<<64 * 9, 256, 0, stream>>>(
            y, wbuf + WQKV_OFF, nullptr, nullptr, nullptr, nullptr,
            q, kb, vT, 1152);

        // attention: 512 blocks, batch pinned to XCD (b = id&7 + 8*((id>>3)&3))
        attn_mfma<<<512, 384, 0, stream>>>(
            q, kb, vT, scale + (size_t)l * H_,
            mixp + (size_t)l * H_ * H_, mixq + (size_t)l * H_ * H_, o);

        // O-proj: 64 x 3 = 192 blocks
        gemm128<2, 384><<<64 * 3, 256, 0, stream>>>(
            o, wbuf + WO_OFF, bo + (size_t)l * DIM_, ls1 + (size_t)l * DIM_,
            xf, nullptr, nullptr, nullptr, nullptr, DIM_);

        ln1w<<<T_, 64, 0, stream>>>(xf, ln2_g + (size_t)l * DIM_, ln2_b + (size_t)l * DIM_, y);

        // MLP1: 64 x 12 = 768 blocks
        gemm128<1, 384><<<64 * 12, 256, 0, stream>>>(
            y, wbuf + W1_OFF, b1 + (size_t)l * MLP_, nullptr,
            nullptr, h, nullptr, nullptr, nullptr, MLP_);

        // MLP2: 64 x 3 = 192 blocks
        gemm128<2, 1536><<<64 * 3, 256, 0, stream>>>(
            h, wbuf + W2_OFF, b2 + (size_t)l * DIM_, ls2 + (size_t)l * DIM_,
            xf, nullptr, nullptr, nullptr, nullptr, DIM_);
    }

    hipMemcpyAsync(d_out, xf, nBytes, hipMemcpyDeviceToDevice, stream);
}